// Round 2
// baseline (90.490 us; speedup 1.0000x reference)
//
#include <hip/hip_runtime.h>
#include <math.h>

// Quanvolution: x[8192,1,32,32] f32, weights[1,8] f32 -> out[8192,1024] f32
// Round 2: streaming structure. No LDS, no __syncthreads. A 1-block pre-kernel
// writes 16 trig constants to d_ws; the main kernel assigns one thread per 4x4
// patch (stride 2 over zero-padded 34x34), loads the patch directly from global
// (predicated at borders), applies RY layer + CNOT ring in registers, and folds
// the second RY layer into the measurement:
//   <Z_w> = (cos(th_w) * Zbar_w - 2 sin(th_w) * Xbar_w) / T
// Zbar via a Walsh tree over st^2; T = sum(st^2) (circuit orthogonal => ||v||^2).

// RY on qubit with bit-mask M (wire 0 = MSB = mask 8), half-angle cos C / sin S.
#define RY(M, C, S)                                                    \
    {                                                                  \
        _Pragma("unroll") for (int k = 0; k < 16; ++k) {               \
            if ((k & (M)) == 0) {                                      \
                float a0 = st[k], a1 = st[k | (M)];                    \
                st[k]       = (C) * a0 - (S) * a1;                     \
                st[k | (M)] = (S) * a0 + (C) * a1;                     \
            }                                                          \
        }                                                              \
    }

// CNOT(control mask MC, target mask MT): swap st[k] <-> st[k|MT] where control
// set. Pure register renaming at -O3.
#define CNOT(MC, MT)                                                   \
    {                                                                  \
        _Pragma("unroll") for (int k = 0; k < 16; ++k) {               \
            if ((k & (MC)) != 0 && (k & (MT)) == 0) {                  \
                float t = st[k];                                       \
                st[k] = st[k | (MT)];                                  \
                st[k | (MT)] = t;                                      \
            }                                                          \
        }                                                              \
    }

__global__ void trig_kernel(const float* __restrict__ w, float* __restrict__ t) {
    int i = threadIdx.x;
    if (i < 4) {
        float h = w[i] * 0.5f;
        t[i]      = cosf(h);
        t[4 + i]  = sinf(h);
        float f = w[4 + i];
        t[8 + i]  = cosf(f);
        t[12 + i] = 2.0f * sinf(f);
    }
}

__global__ __launch_bounds__(256) void quanv_kernel(
    const float* __restrict__ x, const float* __restrict__ trig,
    float* __restrict__ out)
{
    const int tid = threadIdx.x;
    const int b = blockIdx.x;
    const int py = tid >> 4, px = tid & 15;

    const float* img = x + ((size_t)b << 10);
    const int c0 = px << 1;

    // Gather 4x4 patch directly from global; rows >=32 / cols >=32 are zero pad.
    float st[16];
#pragma unroll
    for (int dr = 0; dr < 4; ++dr) {
        const int r = (py << 1) + dr;
        float2 u0 = make_float2(0.f, 0.f);
        float2 u1 = make_float2(0.f, 0.f);
        if (r < 32) {
            const float* rp = img + (r << 5) + c0;
            u0 = *(const float2*)rp;               // cols c0, c0+1 (8B aligned)
            if (c0 < 30) u1 = *(const float2*)(rp + 2);  // cols c0+2, c0+3
        }
        st[dr * 4 + 0] = u0.x;
        st[dr * 4 + 1] = u0.y;
        st[dr * 4 + 2] = u1.x;
        st[dr * 4 + 3] = u1.y;
    }

    // Uniform trig constants (L2-hot after the pre-kernel).
    const float4 ch  = ((const float4*)trig)[0];  // cos(w[0..3]/2)
    const float4 sh  = ((const float4*)trig)[1];  // sin(w[0..3]/2)
    const float4 cf  = ((const float4*)trig)[2];  // cos(w[4..7])
    const float4 sf2 = ((const float4*)trig)[3];  // 2*sin(w[4..7])

    // Layer 1: RY on qubits 0..3 (masks 8,4,2,1).
    RY(8, ch.x, sh.x)
    RY(4, ch.y, sh.y)
    RY(2, ch.z, sh.z)
    RY(1, ch.w, sh.w)

    // CNOT ring: (0,1),(1,2),(2,3),(3,0).
    CNOT(8, 4)
    CNOT(4, 2)
    CNOT(2, 1)
    CNOT(1, 8)

    // Probabilities.
    float p[16];
#pragma unroll
    for (int k = 0; k < 16; ++k) p[k] = st[k] * st[k];

    // Walsh tree: T and the four single-bit signed sums Z_m (m = bit mask).
    float sA[8], dA[8];
#pragma unroll
    for (int i = 0; i < 8; ++i) {
        sA[i] = p[2 * i] + p[2 * i + 1];
        dA[i] = p[2 * i] - p[2 * i + 1];
    }
    float Z1 = ((dA[0] + dA[1]) + (dA[2] + dA[3])) +
               ((dA[4] + dA[5]) + (dA[6] + dA[7]));
    float sB[4], dB[4];
#pragma unroll
    for (int j = 0; j < 4; ++j) {
        sB[j] = sA[2 * j] + sA[2 * j + 1];
        dB[j] = sA[2 * j] - sA[2 * j + 1];
    }
    float Z2 = (dB[0] + dB[1]) + (dB[2] + dB[3]);
    float sC0 = sB[0] + sB[1], dC0 = sB[0] - sB[1];
    float sC1 = sB[2] + sB[3], dC1 = sB[2] - sB[3];
    float Z4 = dC0 + dC1;
    float T  = sC0 + sC1;
    float Z8 = sC0 - sC1;
    float inv = 1.0f / T;

    // Off-diagonal sums X_m = sum_{k: bit m clear} st[k]*st[k|m].
    float X8 = 0.f, X4 = 0.f, X2 = 0.f, X1 = 0.f;
#pragma unroll
    for (int k = 0; k < 16; ++k) {
        if ((k & 8) == 0) X8 = fmaf(st[k], st[k | 8], X8);
        if ((k & 4) == 0) X4 = fmaf(st[k], st[k | 4], X4);
        if ((k & 2) == 0) X2 = fmaf(st[k], st[k | 2], X2);
        if ((k & 1) == 0) X1 = fmaf(st[k], st[k | 1], X1);
    }

    const float e0 = (cf.x * Z8 - sf2.x * X8) * inv;
    const float e1 = (cf.y * Z4 - sf2.y * X4) * inv;
    const float e2 = (cf.z * Z2 - sf2.z * X2) * inv;
    const float e3 = (cf.w * Z1 - sf2.w * X1) * inv;

    // out[b, tid*4 + w] -- coalesced float4 store.
    *(float4*)(out + ((size_t)b << 10) + (tid << 2)) = make_float4(e0, e1, e2, e3);
}

extern "C" void kernel_launch(void* const* d_in, const int* in_sizes, int n_in,
                              void* d_out, int out_size, void* d_ws, size_t ws_size,
                              hipStream_t stream) {
    const float* x = (const float*)d_in[0];
    const float* w = (const float*)d_in[1];
    float* out = (float*)d_out;
    float* trig = (float*)d_ws;  // 16 floats
    const int B = in_sizes[0] >> 10;  // 8192 images

    trig_kernel<<<1, 64, 0, stream>>>(w, trig);
    quanv_kernel<<<B, 256, 0, stream>>>(x, trig, out);
}